// Round 2
// baseline (110.779 us; speedup 1.0000x reference)
//
#include <hip/hip_runtime.h>
#include <math.h>

// Problem constants (reference: N=8192, D=200, k=100)
#define NN 8192
#define DD 200
#define KK 100

// s = b_i + e_j histogram grid: 1024 bins over [-8, 8), width 2^-6 (exact fp)
#define NBINS 1024
#define HSCALE 64.0f
#define BINW 0.015625f
#define CAND_CAP 4096
#define ROW_CAP 1024
#define COL_CAP 1024

// ws layout (4-byte word offsets)
#define OFF_B 0
#define OFF_E 8192
#define OFF_PB 16384   // 2048 per-block partials of sum(exp(b))
#define OFF_PE 18432   // 2048 per-block partials of sum(exp(e))

// Global histograms: [0,1024)=hist_b, [1024,2048)=hist_e.
// Zero at module load (.bss); k_tail re-zeroes immediately after consuming,
// so every k_be launch sees zeros (stream order: k_tail(i) < k_be(i+1)).
__device__ unsigned g_hist[2 * NBINS];

// K1: b[i] = G[i,:]·wb, e[i] = G[i,:]·we. One wave per row; 50 lanes × float4.
// R1: absorbs the per-element staging work that used to serialize on k_tail's
// single CU — exp partials (deterministic per-block order), histogram bins
// (device-scope atomics, ~8K increments over ~150 hot bins per array).
__global__ __launch_bounds__(256) void k_be(const float* __restrict__ G,
                                            const float* __restrict__ wb,
                                            const float* __restrict__ we,
                                            float* __restrict__ wsf) {
    __shared__ float seb[4], see[4];
    int gid = blockIdx.x * 256 + threadIdx.x;
    int row = gid >> 6;
    int lane = gid & 63;
    int wave = threadIdx.x >> 6;
    float pb = 0.f, pe = 0.f;
    if (lane < 50) {
        float4 g = ((const float4*)(G + (size_t)row * DD))[lane];
        float4 B = ((const float4*)wb)[lane];
        float4 E = ((const float4*)we)[lane];
        pb = fmaf(g.x, B.x, fmaf(g.y, B.y, fmaf(g.z, B.z, g.w * B.w)));
        pe = fmaf(g.x, E.x, fmaf(g.y, E.y, fmaf(g.z, E.z, g.w * E.w)));
    }
    for (int off = 32; off; off >>= 1) {
        pb += __shfl_xor(pb, off, 64);
        pe += __shfl_xor(pe, off, 64);
    }
    if (lane == 0) {
        wsf[OFF_B + row] = pb;
        wsf[OFF_E + row] = pe;
        // exact same bin math as before (fmaf + clamp) -> identical t*
        int p = (int)fmaf(pb, HSCALE, 512.f);
        atomicAdd(&g_hist[min(max(p, 0), NBINS - 1)], 1u);
        int q = (int)fmaf(pe, HSCALE, 512.f);
        atomicAdd(&g_hist[NBINS + min(max(q, 0), NBINS - 1)], 1u);
        seb[wave] = expf(pb);
        see[wave] = expf(pe);
    }
    __syncthreads();
    if (threadIdx.x == 0) {
        wsf[OFF_PB + blockIdx.x] = (seb[0] + seb[1]) + (seb[2] + seb[3]);
        wsf[OFF_PE + blockIdx.x] = (see[0] + see[1]) + (see[2] + see[3]);
    }
}

// K2: single block, 1024 threads. Staging is now a pure copy; hist/sums/maxes
// arrive precomputed. Descent / candidate / pair / rank logic unchanged
// (identical integer histogram math -> identical thresholds and indices).
__global__ __launch_bounds__(1024) void k_tail(const float* __restrict__ wsf,
                                               float* __restrict__ out) {
    __shared__ float    b_s[NN];          // 32 KB
    __shared__ float    e_s[NN];          // 32 KB
    __shared__ float    cv[CAND_CAP];     // 16 KB
    __shared__ unsigned ci[CAND_CAP];     // 16 KB
    __shared__ unsigned sfx[NBINS];       // suffix sums of hist_e
    __shared__ unsigned hbl[NBINS];       // hist_b
    __shared__ int      rows_s[ROW_CAP];
    __shared__ float    rowb_s[ROW_CAP];
    __shared__ int      cols_s[COL_CAP];
    __shared__ float    cole_s[COL_CAP];
    __shared__ float    fr_sb[16], fr_se[16];
    __shared__ int      fr_eb[16], fr_bb[16];
    __shared__ unsigned wred[16], wtail_s[16];
    __shared__ unsigned nrows_s, ncols_s, ncand_s;
    __shared__ int      lo_s;
    __shared__ float    sums_s[4];        // sb, se, emax_ub, bmax_ub

    int tid = threadIdx.x, wave = tid >> 6, lane = tid & 63;
    if (tid == 0) { nrows_s = 0u; ncols_s = 0u; ncand_s = 0u; lo_s = 0; }

    // ---- Stage b,e (pure float4 copy; no per-element compute).
    const float4* b4 = (const float4*)(wsf + OFF_B);
    const float4* e4 = (const float4*)(wsf + OFF_E);
    for (int i = tid; i < NN / 4; i += 1024) {        // 2 iterations
        ((float4*)b_s)[i] = b4[i];
        ((float4*)e_s)[i] = e4[i];
    }

    // ---- Load hists from global; zero-after-read (thread t zeroes exactly
    // the words it read — no cross-thread hazard, no extra sync).
    unsigned hb = g_hist[tid];
    unsigned he = g_hist[NBINS + tid];
    g_hist[tid] = 0u;
    g_hist[NBINS + tid] = 0u;
    hbl[tid] = hb;

    // ---- Reduce per-block exp partials (deterministic fixed order) and
    // top-occupied-bin upper bounds for emax/bmax (conservative supersets).
    float psb = wsf[OFF_PB + tid] + wsf[OFF_PB + 1024 + tid];
    float pse = wsf[OFF_PE + tid] + wsf[OFF_PE + 1024 + tid];
    int ebin = (he != 0u) ? tid : -1;
    int bbin = (hb != 0u) ? tid : -1;
    for (int off = 32; off; off >>= 1) {
        psb += __shfl_xor(psb, off, 64);
        pse += __shfl_xor(pse, off, 64);
        ebin = max(ebin, __shfl_xor(ebin, off, 64));
        bbin = max(bbin, __shfl_xor(bbin, off, 64));
    }
    if (lane == 0) { fr_sb[wave] = psb; fr_se[wave] = pse; fr_eb[wave] = ebin; fr_bb[wave] = bbin; }
    __syncthreads();
    if (tid == 0) {
        float a = 0.f, b = 0.f; int c = -1, d = -1;
        for (int i = 0; i < 16; ++i) {
            a += fr_sb[i]; b += fr_se[i];
            c = max(c, fr_eb[i]); d = max(d, fr_bb[i]);
        }
        sums_s[0] = a; sums_s[1] = b;
        sums_s[2] = -8.0f + (float)(c + 1) * BINW;   // >= true emax
        sums_s[3] = -8.0f + (float)(d + 1) * BINW;   // >= true bmax
    }

    // ---- Suffix-sum hist_e: intra-wave shfl_down + wave tails (v from reg).
    unsigned v = he;
    for (int off = 1; off < 64; off <<= 1) {
        unsigned t = __shfl_down(v, off, 64);
        if (lane + off < 64) v += t;
    }
    if (lane == 0) wtail_s[wave] = v;
    __syncthreads();
    if (tid == 0) {
        unsigned acc = 0, tails[16];
        for (int w = 15; w >= 0; --w) { tails[w] = acc; acc += wtail_s[w]; }
        for (int w = 0; w < 16; ++w) wtail_s[w] = tails[w];
    }
    __syncthreads();
    sfx[tid] = v + wtail_s[wave];
    __syncthreads();

    // ---- 16-ary descent for largest t with cnt(t) >= 2*KK (identical
    // integer math and t* as all prior rounds).
    const unsigned TARGET = 2u * KK;
    int chunk = 64;
    for (int round = 0; round < 2; ++round) {
        int t = lo_s + (wave + 1) * chunk;
        unsigned c = 0;
        for (int k = 0; k < 16; ++k) {
            int p = lane + (k << 6);
            int idx = t + 512 - p;
            unsigned sv = (idx <= 0) ? sfx[0] : ((idx > NBINS - 1) ? 0u : sfx[idx]);
            c += hbl[p] * sv;
        }
        for (int off = 32; off; off >>= 1) c += __shfl_xor(c, off, 64);
        if (lane == 0) wred[wave] = c;
        __syncthreads();
        if (tid == 0) {
            for (int w = 15; w >= 0; --w)
                if (wred[w] >= TARGET) { lo_s += (w + 1) * chunk; break; }
        }
        __syncthreads();
        chunk >>= 4;   // 64 -> 4
    }
    {   // bracket is 4 wide: evaluate lo+1..lo+3 with waves 0..2
        int t = lo_s + wave + 1;
        if (wave < 3) {
            unsigned c = 0;
            for (int k = 0; k < 16; ++k) {
                int p = lane + (k << 6);
                int idx = t + 512 - p;
                unsigned sv = (idx <= 0) ? sfx[0] : ((idx > NBINS - 1) ? 0u : sfx[idx]);
                c += hbl[p] * sv;
            }
            for (int off = 32; off; off >>= 1) c += __shfl_xor(c, off, 64);
            if (lane == 0) wred[wave] = c;
        }
        __syncthreads();
        if (tid == 0) {
            for (int w = 2; w >= 0; --w)
                if (wred[w] >= TARGET) { lo_s += w + 1; break; }
        }
        __syncthreads();
    }
    float thr = -8.0f + (float)(lo_s - 1) * BINW;   // one-bin safety margin
    float emax = sums_s[2], bmax = sums_s[3];

    // ---- Row and column candidate lists (conservative supersets).
    for (int i = tid; i < NN; i += 1024) {
        float bv = b_s[i];
        if (bv + emax >= thr) {
            unsigned pos = atomicAdd(&nrows_s, 1u);
            if (pos < ROW_CAP) { rows_s[pos] = i; rowb_s[pos] = bv; }
        }
        float ev = e_s[i];
        if (ev + bmax >= thr) {
            unsigned pos = atomicAdd(&ncols_s, 1u);
            if (pos < COL_CAP) { cols_s[pos] = i; cole_s[pos] = ev; }
        }
    }
    __syncthreads();
    int nr = (int)min(nrows_s, (unsigned)ROW_CAP);
    int nc = (int)min(ncols_s, (unsigned)COL_CAP);

    // ---- Pair scan over nr x nc candidate grid, upper triangle (j >= r).
    int tot = nr * nc;
    for (int idx = tid; idx < tot; idx += 1024) {
        int ri = idx / nc, cj = idx - ri * nc;
        int r = rows_s[ri], j = cols_s[cj];
        if (j < r) continue;
        float s = rowb_s[ri] + cole_s[cj];
        if (s >= thr) {
            unsigned pos = atomicAdd(&ncand_s, 1u);
            if (pos < CAND_CAP) {
                cv[pos] = s;
                ci[pos] = ((unsigned)r << 13) | (unsigned)j;
            }
        }
    }
    __syncthreads();

    // ---- Rank-based top-100 (jax order: value desc, flat index asc).
    unsigned M = min(ncand_s, (unsigned)CAND_CAP);
    float inv_den = 1.0f / (sums_s[0] * sums_s[1]);
    for (unsigned c2 = tid; c2 < M; c2 += 1024) {
        float vv = cv[c2];
        unsigned fi = ci[c2];
        int rank = 0;
        for (unsigned m = 0; m < M; ++m) {
            float vm = cv[m];
            rank += (vm > vv) || (vm == vv && ci[m] < fi);
        }
        if (rank < KK) {
            out[2 * rank]     = (float)(fi >> 13);
            out[2 * rank + 1] = (float)(fi & 8191u);
            out[200 + rank]   = expf(vv) * inv_den;
        }
    }
}

extern "C" void kernel_launch(void* const* d_in, const int* in_sizes, int n_in,
                              void* d_out, int out_size, void* d_ws, size_t ws_size,
                              hipStream_t stream) {
    const float* G  = (const float*)d_in[0];
    const float* wb = (const float*)d_in[1];
    const float* we = (const float*)d_in[2];
    float* out = (float*)d_out;
    float* wsf = (float*)d_ws;

    hipLaunchKernelGGL(k_be, dim3(2048), dim3(256), 0, stream, G, wb, we, wsf);
    hipLaunchKernelGGL(k_tail, dim3(1), dim3(1024), 0, stream, wsf, out);
}

// Round 3
// 79.221 us; speedup vs baseline: 1.3984x; 1.3984x over previous
//
#include <hip/hip_runtime.h>
#include <math.h>

// Problem constants (reference: N=8192, D=200, k=100)
#define NN 8192
#define DD 200
#define KK 100

// s = b_i + e_j histogram grid: 1024 bins over [-8, 8), width 2^-6 (exact fp)
#define NBINS 1024
#define HSCALE 64.0f
#define BINW 0.015625f
#define CAND_CAP 4096
#define ROW_CAP 1024
#define COL_CAP 1024

// ws layout (4-byte word offsets)
#define OFF_B 0
#define OFF_E 8192
#define OFF_PB 16384   // 2048 per-block partials of sum(exp(b))
#define OFF_PE 18432   // 2048 per-block partials of sum(exp(e))

// K1: b[i] = G[i,:]·wb, e[i] = G[i,:]·we. One wave per row; 50 lanes × float4.
// Keeps R2's free exp-partial offload (no atomics — R2 proved the atomic
// histogram costs ~33 µs of hot-line serialization; reverted).
__global__ __launch_bounds__(256) void k_be(const float* __restrict__ G,
                                            const float* __restrict__ wb,
                                            const float* __restrict__ we,
                                            float* __restrict__ wsf) {
    __shared__ float seb[4], see[4];
    int gid = blockIdx.x * 256 + threadIdx.x;
    int row = gid >> 6;
    int lane = gid & 63;
    int wave = threadIdx.x >> 6;
    float pb = 0.f, pe = 0.f;
    if (lane < 50) {
        float4 g = ((const float4*)(G + (size_t)row * DD))[lane];
        float4 B = ((const float4*)wb)[lane];
        float4 E = ((const float4*)we)[lane];
        pb = fmaf(g.x, B.x, fmaf(g.y, B.y, fmaf(g.z, B.z, g.w * B.w)));
        pe = fmaf(g.x, E.x, fmaf(g.y, E.y, fmaf(g.z, E.z, g.w * E.w)));
    }
    for (int off = 32; off; off >>= 1) {
        pb += __shfl_xor(pb, off, 64);
        pe += __shfl_xor(pe, off, 64);
    }
    if (lane == 0) {
        wsf[OFF_B + row] = pb;
        wsf[OFF_E + row] = pe;
        seb[wave] = expf(pb);
        see[wave] = expf(pe);
    }
    __syncthreads();
    if (threadIdx.x == 0) {
        wsf[OFF_PB + blockIdx.x] = (seb[0] + seb[1]) + (seb[2] + seb[3]);
        wsf[OFF_PE + blockIdx.x] = (see[0] + see[1]) + (see[2] + see[3]);
    }
}

// K2: single block, 1024 threads. Staging = copy + LDS hist (cheap, per R2
// ablation); exp sums arrive as per-block partials; maxes from hist top bins.
__global__ __launch_bounds__(1024) void k_tail(const float* __restrict__ wsf,
                                               float* __restrict__ out) {
    __shared__ float    b_s[NN];          // 32 KB
    __shared__ float    e_s[NN];          // 32 KB
    __shared__ float    cv[CAND_CAP];     // 16 KB
    __shared__ unsigned ci[CAND_CAP];     // 16 KB
    __shared__ unsigned sfx[NBINS];       // hist_e -> suffix sums (in place)
    __shared__ unsigned hbl[NBINS];       // hist_b
    __shared__ int      rows_s[ROW_CAP];
    __shared__ float    rowb_s[ROW_CAP];
    __shared__ int      cols_s[COL_CAP];
    __shared__ float    cole_s[COL_CAP];
    __shared__ float    fr_sb[16], fr_se[16];
    __shared__ int      fr_eb[16], fr_bb[16];
    __shared__ unsigned wred[16], wtail_s[16];
    __shared__ unsigned nrows_s, ncols_s, ncand_s;
    __shared__ int      lo_s;
    __shared__ float    sums_s[4];        // sb, se, emax_ub, bmax_ub

    int tid = threadIdx.x, wave = tid >> 6, lane = tid & 63;

    sfx[tid] = 0u; hbl[tid] = 0u;
    if (tid == 0) { nrows_s = 0u; ncols_s = 0u; ncand_s = 0u; lo_s = 0; }
    __syncthreads();

    // ---- Stage b,e (float4 copy) + LDS-atomic hists (no expf, no fmax).
    const float4* b4 = (const float4*)(wsf + OFF_B);
    const float4* e4 = (const float4*)(wsf + OFF_E);
    for (int i = tid; i < NN / 4; i += 1024) {        // 2 iterations
        float4 bv = b4[i], ev = e4[i];
        ((float4*)b_s)[i] = bv;
        ((float4*)e_s)[i] = ev;
        int p;
        p = (int)fmaf(bv.x, HSCALE, 512.f); atomicAdd(&hbl[min(max(p,0),NBINS-1)], 1u);
        p = (int)fmaf(bv.y, HSCALE, 512.f); atomicAdd(&hbl[min(max(p,0),NBINS-1)], 1u);
        p = (int)fmaf(bv.z, HSCALE, 512.f); atomicAdd(&hbl[min(max(p,0),NBINS-1)], 1u);
        p = (int)fmaf(bv.w, HSCALE, 512.f); atomicAdd(&hbl[min(max(p,0),NBINS-1)], 1u);
        p = (int)fmaf(ev.x, HSCALE, 512.f); atomicAdd(&sfx[min(max(p,0),NBINS-1)], 1u);
        p = (int)fmaf(ev.y, HSCALE, 512.f); atomicAdd(&sfx[min(max(p,0),NBINS-1)], 1u);
        p = (int)fmaf(ev.z, HSCALE, 512.f); atomicAdd(&sfx[min(max(p,0),NBINS-1)], 1u);
        p = (int)fmaf(ev.w, HSCALE, 512.f); atomicAdd(&sfx[min(max(p,0),NBINS-1)], 1u);
    }

    // ---- Reduce per-block exp partials (fixed order, R2-validated absmax 0).
    float psb = wsf[OFF_PB + tid] + wsf[OFF_PB + 1024 + tid];
    float pse = wsf[OFF_PE + tid] + wsf[OFF_PE + 1024 + tid];
    for (int off = 32; off; off >>= 1) {
        psb += __shfl_xor(psb, off, 64);
        pse += __shfl_xor(pse, off, 64);
    }
    if (lane == 0) { fr_sb[wave] = psb; fr_se[wave] = pse; }
    __syncthreads();    // hist atomics + fr_sb/fr_se complete

    // ---- Top-occupied-bin upper bounds for emax/bmax + suffix-scan setup.
    unsigned hb = hbl[tid];
    unsigned he = sfx[tid];
    int ebin = (he != 0u) ? tid : -1;
    int bbin = (hb != 0u) ? tid : -1;
    for (int off = 32; off; off >>= 1) {
        ebin = max(ebin, __shfl_xor(ebin, off, 64));
        bbin = max(bbin, __shfl_xor(bbin, off, 64));
    }
    if (lane == 0) { fr_eb[wave] = ebin; fr_bb[wave] = bbin; }
    // intra-wave inclusive-from-the-right scan of hist_e
    unsigned v = he;
    for (int off = 1; off < 64; off <<= 1) {
        unsigned t = __shfl_down(v, off, 64);
        if (lane + off < 64) v += t;
    }
    if (lane == 0) wtail_s[wave] = v;
    __syncthreads();
    if (tid == 0) {
        float a = 0.f, b = 0.f; int c = -1, d = -1;
        for (int i = 0; i < 16; ++i) {
            a += fr_sb[i]; b += fr_se[i];
            c = max(c, fr_eb[i]); d = max(d, fr_bb[i]);
        }
        sums_s[0] = a; sums_s[1] = b;
        sums_s[2] = -8.0f + (float)(c + 1) * BINW;   // >= true emax
        sums_s[3] = -8.0f + (float)(d + 1) * BINW;   // >= true bmax
        unsigned acc = 0, tails[16];
        for (int w = 15; w >= 0; --w) { tails[w] = acc; acc += wtail_s[w]; }
        for (int w = 0; w < 16; ++w) wtail_s[w] = tails[w];
    }
    __syncthreads();
    sfx[tid] = v + wtail_s[wave];
    __syncthreads();

    // ---- 16-ary descent for largest t with cnt(t) >= 2*KK (identical
    // integer math and t* as all prior rounds).
    const unsigned TARGET = 2u * KK;
    int chunk = 64;
    for (int round = 0; round < 2; ++round) {
        int t = lo_s + (wave + 1) * chunk;
        unsigned c = 0;
        for (int k = 0; k < 16; ++k) {
            int p = lane + (k << 6);
            int idx = t + 512 - p;
            unsigned sv = (idx <= 0) ? sfx[0] : ((idx > NBINS - 1) ? 0u : sfx[idx]);
            c += hbl[p] * sv;
        }
        for (int off = 32; off; off >>= 1) c += __shfl_xor(c, off, 64);
        if (lane == 0) wred[wave] = c;
        __syncthreads();
        if (tid == 0) {
            for (int w = 15; w >= 0; --w)
                if (wred[w] >= TARGET) { lo_s += (w + 1) * chunk; break; }
        }
        __syncthreads();
        chunk >>= 4;   // 64 -> 4
    }
    {   // bracket is 4 wide: evaluate lo+1..lo+3 with waves 0..2
        int t = lo_s + wave + 1;
        if (wave < 3) {
            unsigned c = 0;
            for (int k = 0; k < 16; ++k) {
                int p = lane + (k << 6);
                int idx = t + 512 - p;
                unsigned sv = (idx <= 0) ? sfx[0] : ((idx > NBINS - 1) ? 0u : sfx[idx]);
                c += hbl[p] * sv;
            }
            for (int off = 32; off; off >>= 1) c += __shfl_xor(c, off, 64);
            if (lane == 0) wred[wave] = c;
        }
        __syncthreads();
        if (tid == 0) {
            for (int w = 2; w >= 0; --w)
                if (wred[w] >= TARGET) { lo_s += w + 1; break; }
        }
        __syncthreads();
    }
    float thr = -8.0f + (float)(lo_s - 1) * BINW;   // one-bin safety margin
    float emax = sums_s[2], bmax = sums_s[3];

    // ---- Row and column candidate lists (conservative supersets).
    for (int i = tid; i < NN; i += 1024) {
        float bv = b_s[i];
        if (bv + emax >= thr) {
            unsigned pos = atomicAdd(&nrows_s, 1u);
            if (pos < ROW_CAP) { rows_s[pos] = i; rowb_s[pos] = bv; }
        }
        float ev = e_s[i];
        if (ev + bmax >= thr) {
            unsigned pos = atomicAdd(&ncols_s, 1u);
            if (pos < COL_CAP) { cols_s[pos] = i; cole_s[pos] = ev; }
        }
    }
    __syncthreads();
    int nr = (int)min(nrows_s, (unsigned)ROW_CAP);
    int nc = (int)min(ncols_s, (unsigned)COL_CAP);

    // ---- Pair scan over nr x nc candidate grid, upper triangle (j >= r).
    int tot = nr * nc;
    for (int idx = tid; idx < tot; idx += 1024) {
        int ri = idx / nc, cj = idx - ri * nc;
        int r = rows_s[ri], j = cols_s[cj];
        if (j < r) continue;
        float s = rowb_s[ri] + cole_s[cj];
        if (s >= thr) {
            unsigned pos = atomicAdd(&ncand_s, 1u);
            if (pos < CAND_CAP) {
                cv[pos] = s;
                ci[pos] = ((unsigned)r << 13) | (unsigned)j;
            }
        }
    }
    __syncthreads();

    // ---- Rank-based top-100 (jax order: value desc, flat index asc).
    unsigned M = min(ncand_s, (unsigned)CAND_CAP);
    float inv_den = 1.0f / (sums_s[0] * sums_s[1]);
    for (unsigned c2 = tid; c2 < M; c2 += 1024) {
        float vv = cv[c2];
        unsigned fi = ci[c2];
        int rank = 0;
        for (unsigned m = 0; m < M; ++m) {
            float vm = cv[m];
            rank += (vm > vv) || (vm == vv && ci[m] < fi);
        }
        if (rank < KK) {
            out[2 * rank]     = (float)(fi >> 13);
            out[2 * rank + 1] = (float)(fi & 8191u);
            out[200 + rank]   = expf(vv) * inv_den;
        }
    }
}

extern "C" void kernel_launch(void* const* d_in, const int* in_sizes, int n_in,
                              void* d_out, int out_size, void* d_ws, size_t ws_size,
                              hipStream_t stream) {
    const float* G  = (const float*)d_in[0];
    const float* wb = (const float*)d_in[1];
    const float* we = (const float*)d_in[2];
    float* out = (float*)d_out;
    float* wsf = (float*)d_ws;

    hipLaunchKernelGGL(k_be, dim3(2048), dim3(256), 0, stream, G, wb, we, wsf);
    hipLaunchKernelGGL(k_tail, dim3(1), dim3(1024), 0, stream, wsf, out);
}